// Round 7
// baseline (392.124 us; speedup 1.0000x reference)
//
#include <hip/hip_runtime.h>

#define BATCH 32
#define SEQT  2048
#define INSZ  256
#define RSV   512
#define MTOT  (BATCH * SEQT)   // 65536 GEMM rows
#define BMR 512                // m rows per gemm block
#define BNR 64                 // r cols per gemm block
#define LSA 40                 // fallback A LDS row stride (f16)
#define LOPLANE 131072         // f16 offset of lo plane in W16T (16384 chunks * 8)

#define K2LOG2E 2.8853900817779268f  // 2*log2(e)

using f16x8 = __attribute__((ext_vector_type(8))) _Float16;
using f16x4 = __attribute__((ext_vector_type(4))) _Float16;
using f32x4 = __attribute__((ext_vector_type(4))) float;

typedef __attribute__((address_space(1))) unsigned int as1_u32;
typedef __attribute__((address_space(3))) unsigned int as3_u32;
#define GLDS16(gp, lp) __builtin_amdgcn_global_load_lds((as1_u32*)(gp), (as3_u32*)(lp), 16, 0, 0)

// s' = tanh(d*s + u) via exp2; dK = d*2log2e.
static __device__ __forceinline__ float esn_step(float s, float u, float dK) {
    float z  = __builtin_fmaf(dK, s, u * K2LOG2E);
    float e  = __builtin_amdgcn_exp2f(z);
    float rc = __builtin_amdgcn_rcpf(1.0f + e);
    return __builtin_fmaf(-2.0f, rc, 1.0f);
}

// ---------------- fast path ----------------

// W [512][256] fp32 -> W16T hi/lo f16 planes in fragment-chunk order.
// Chunk i: bn=i>>11, c=i&2047 with c=(ks*4+q)*64 + r (r fast => lane-consecutive
// 16B granules on LDS fragment reads). Chunk holds W[bn*64+r][ks*32+q*8 .. +7].
__global__ __launch_bounds__(256) void esn_convw(const float* __restrict__ W,
                                                 _Float16* __restrict__ W16T) {
    const int i = blockIdx.x * 256 + threadIdx.x;   // 0..16383
    const int bn = i >> 11, c = i & 2047;
    const int ks = c >> 8, q = (c >> 6) & 3, r = c & 63;
    const float* src = W + (size_t)(bn * BNR + r) * INSZ + ks * 32 + q * 8;
    float4 v0 = *(const float4*)src;
    float4 v1 = *(const float4*)(src + 4);
    float w8[8] = {v0.x, v0.y, v0.z, v0.w, v1.x, v1.y, v1.z, v1.w};
    f16x8 h, l;
    #pragma unroll
    for (int j = 0; j < 8; ++j) {
        _Float16 hh = (_Float16)w8[j];
        h[j] = hh;
        l[j] = (_Float16)(w8[j] - (float)hh);
    }
    *(f16x8*)(W16T + (size_t)i * 8) = h;
    *(f16x8*)(W16T + LOPLANE + (size_t)i * 8) = l;
}

// W-stationary GEMM: u[m][r] = sum_k X[m][k]*W[r][k], 2-pass f16 hi/lo.
// Block = (mg: 512 m-rows, bn: 64 r). W bn-slice staged to LDS ONCE via
// global_load_lds; then ZERO barriers: A-frags direct from global (depth-2 ks
// prefetch), MFMA from read-only LDS. 4 waves x 128 m-rows each. Output u16 f16.
__global__ __launch_bounds__(256) void esn_gemm_f(const float* __restrict__ X,
                                                  const _Float16* __restrict__ W16T,
                                                  _Float16* __restrict__ U16) {
    __shared__ _Float16 Wsh[2 * 16384];   // 64 KB: [hi|lo][c][8]

    const int tid  = threadIdx.x;
    const int lane = tid & 63;
    const int wid  = tid >> 6;
    // chunked XCD swizzle: the 8 bn-siblings of one m-group land on one XCD
    const int lg = (blockIdx.x & 7) * 128 + (blockIdx.x >> 3);   // 0..1023
    const int mg = lg >> 3, bn = lg & 7;

    // ---- stage W[bn] hi+lo (one time) ----
    const _Float16* wsrc = W16T + (size_t)bn * 16384;
    #pragma unroll
    for (int i = 0; i < 8; ++i) {
        const int cb = i * 256 + wid * 64;   // wave-uniform chunk base
        GLDS16(wsrc + (size_t)(cb + lane) * 8, &Wsh[cb * 8]);
        GLDS16(wsrc + LOPLANE + (size_t)(cb + lane) * 8, &Wsh[16384 + cb * 8]);
    }
    __syncthreads();   // only barrier in the kernel

    const int q = lane >> 4;
    const float* xbase = X + (size_t)(mg * BMR + wid * 128 + (lane & 15)) * INSZ + q * 8;

    for (int ch = 0; ch < 4; ++ch) {   // 4 chunks of 32 m-rows per wave
        f32x4 acc[2][4] = {};
        // depth-2 ks prefetch: slots for ks and ks+1
        float4 xrA[2][2], xrB[2][2];
        #pragma unroll
        for (int mf = 0; mf < 2; ++mf) {
            const float* xp = xbase + (size_t)(ch * 32 + mf * 16) * INSZ;
            xrA[mf][0] = *(const float4*)xp;       xrA[mf][1] = *(const float4*)(xp + 4);
            xrB[mf][0] = *(const float4*)(xp + 32); xrB[mf][1] = *(const float4*)(xp + 36);
        }
        #pragma unroll
        for (int ks = 0; ks < 8; ++ks) {
            // convert current slot -> f16 frags
            f16x8 af[2];
            #pragma unroll
            for (int mf = 0; mf < 2; ++mf) {
                float4 x0 = (ks & 1) ? xrB[mf][0] : xrA[mf][0];
                float4 x1 = (ks & 1) ? xrB[mf][1] : xrA[mf][1];
                float x8[8] = {x0.x, x0.y, x0.z, x0.w, x1.x, x1.y, x1.z, x1.w};
                #pragma unroll
                for (int j = 0; j < 8; ++j) af[mf][j] = (_Float16)x8[j];
            }
            // refill the just-freed slot with ks+2
            if (ks + 2 < 8) {
                #pragma unroll
                for (int mf = 0; mf < 2; ++mf) {
                    const float* xp = xbase + (size_t)(ch * 32 + mf * 16) * INSZ + (ks + 2) * 32;
                    if (ks & 1) { xrB[mf][0] = *(const float4*)xp; xrB[mf][1] = *(const float4*)(xp + 4); }
                    else        { xrA[mf][0] = *(const float4*)xp; xrA[mf][1] = *(const float4*)(xp + 4); }
                }
            }
            // W frags (lane-consecutive 16B granules -> conflict-free) + MFMA
            #pragma unroll
            for (int nf = 0; nf < 4; ++nf) {
                const int coff = (((ks * 4 + q) * 64) + nf * 16 + (lane & 15)) * 8;
                f16x8 wh = *(const f16x8*)&Wsh[coff];
                f16x8 wl = *(const f16x8*)&Wsh[16384 + coff];
                // swapped operands: lane's reg-run = 4 consecutive r
                acc[0][nf] = __builtin_amdgcn_mfma_f32_16x16x32_f16(wh, af[0], acc[0][nf], 0, 0, 0);
                acc[1][nf] = __builtin_amdgcn_mfma_f32_16x16x32_f16(wh, af[1], acc[1][nf], 0, 0, 0);
                acc[0][nf] = __builtin_amdgcn_mfma_f32_16x16x32_f16(wl, af[0], acc[0][nf], 0, 0, 0);
                acc[1][nf] = __builtin_amdgcn_mfma_f32_16x16x32_f16(wl, af[1], acc[1][nf], 0, 0, 0);
            }
        }
        // epilogue: lane holds m = lane&15 col, r-run = q*4+j; packed f16x4 stores
        #pragma unroll
        for (int mf = 0; mf < 2; ++mf) {
            const int gm = mg * BMR + wid * 128 + ch * 32 + mf * 16 + (lane & 15);
            #pragma unroll
            for (int nf = 0; nf < 4; ++nf) {
                const int gr = bn * BNR + nf * 16 + q * 4;
                f16x4 o;
                #pragma unroll
                for (int j = 0; j < 4; ++j) o[j] = (_Float16)acc[mf][nf][j];
                *(f16x4*)(U16 + (size_t)gm * RSV + gr) = o;
            }
        }
    }
}

// Parallel-in-time recurrence: 16 segments of 128 steps, 32-step warmup from zero
// (|d|<=0.5 => warmup error <= 2^-32). u16 [b][t][r]: coalesced 128B wave reads;
// OUT writes coalesced 256B. 1024 blocks -> 16 waves/CU TLP, 17-deep prefetch ILP.
__global__ __launch_bounds__(256) void esn_recur_f(const _Float16* __restrict__ U16,
                                                   const float* __restrict__ D,
                                                   float* __restrict__ OUT) {
    const int tid  = threadIdx.x;
    const int b    = blockIdx.x >> 5;
    const int seg  = (blockIdx.x >> 1) & 15;
    const int half = blockIdx.x & 1;
    const int r    = half * 256 + tid;

    const _Float16* ub = U16 + (size_t)b * SEQT * RSV + r;
    float* ob = OUT + (size_t)b * SEQT * RSV + r;
    const float dK = D[r] * K2LOG2E;
    const int t0 = seg * 128;

    float s = 0.0f;
    if (seg) {
        #pragma unroll 8
        for (int k = 0; k < 32; ++k)
            s = esn_step(s, (float)ub[(size_t)(t0 - 31 + k) * RSV], dK);
    }

    _Float16 bufA[8], bufB[8];
    #pragma unroll
    for (int j = 0; j < 8; ++j) bufA[j] = ub[(size_t)(t0 + 1 + j) * RSV];
    #pragma unroll
    for (int j = 0; j < 8; ++j) bufB[j] = ub[(size_t)(t0 + 9 + j) * RSV];

#define PROC8F(buf, tt) do {                                  \
    _Pragma("unroll")                                         \
    for (int j = 0; j < 8; ++j) {                             \
        s = esn_step(s, (float)buf[j], dK);                   \
        ob[(size_t)((tt) + j) * RSV] = s;                     \
        int idx = (tt) + j + 17;                              \
        idx = idx < SEQT ? idx : SEQT - 1;                    \
        buf[j] = ub[(size_t)idx * RSV];                       \
    }                                                         \
} while (0)

    int t = t0;
    for (int it = 0; it < 8; ++it) {   // 8*16 = 128 steps
        PROC8F(bufA, t);
        PROC8F(bufB, t + 8);
        t += 16;
    }
#undef PROC8F
    if (seg == 15) ob[(size_t)(SEQT - 1) * RSV] = 0.0f;
}

// ---------------- fallback path (no workspace; round-2 kernels, in-place) ----------------

__global__ __launch_bounds__(256) void esn_gemm_fb(const float* __restrict__ X,
                                                   const float* __restrict__ W,
                                                   float* __restrict__ U) {
    __shared__ _Float16 Ash[128 * LSA];
    __shared__ _Float16 Bsh[128 * 72];

    const int tid  = threadIdx.x;
    const int lane = tid & 63;
    const int wid  = tid >> 6;
    const int wr   = wid >> 1, wc = wid & 1;
    const int bm   = blockIdx.x >> 2, bn = blockIdx.x & 3;
    const int srow = tid >> 3;
    const int scol = (tid & 7) * 4;

    f32x4 acc[4][4] = {};

    for (int ks = 0; ks < 8; ++ks) {
        __syncthreads();
        #pragma unroll
        for (int p = 0; p < 4; ++p) {
            const int row = srow + p * 32;
            float4 av = *(const float4*)(X + (size_t)(bm * 128 + row) * INSZ + ks * 32 + scol);
            float4 bv = *(const float4*)(W + (size_t)(bn * 128 + row) * INSZ + ks * 32 + scol);
            float a4[4] = {av.x, av.y, av.z, av.w};
            float b4[4] = {bv.x, bv.y, bv.z, bv.w};
            f16x4 ah, bh, bl;
            #pragma unroll
            for (int j = 0; j < 4; ++j) {
                ah[j] = (_Float16)a4[j];
                _Float16 h = (_Float16)b4[j];
                bh[j] = h;
                bl[j] = (_Float16)(b4[j] - (float)h);
            }
            *(f16x4*)&Ash[row * LSA + scol] = ah;
            *(f16x4*)&Bsh[row * 72 + scol] = bh;
            *(f16x4*)&Bsh[row * 72 + 32 + scol] = bl;
        }
        __syncthreads();

        f16x8 af[4], bfh[4], bfl[4];
        #pragma unroll
        for (int m = 0; m < 4; ++m)
            af[m] = *(const f16x8*)&Ash[(wr * 64 + m * 16 + (lane & 15)) * LSA + (lane >> 4) * 8];
        #pragma unroll
        for (int n = 0; n < 4; ++n) {
            const _Float16* p = &Bsh[(wc * 64 + n * 16 + (lane & 15)) * 72 + (lane >> 4) * 8];
            bfh[n] = *(const f16x8*)p;
            bfl[n] = *(const f16x8*)(p + 32);
        }
        #pragma unroll
        for (int m = 0; m < 4; ++m)
            #pragma unroll
            for (int n = 0; n < 4; ++n) {
                acc[m][n] = __builtin_amdgcn_mfma_f32_16x16x32_f16(af[m], bfh[n], acc[m][n], 0, 0, 0);
                acc[m][n] = __builtin_amdgcn_mfma_f32_16x16x32_f16(af[m], bfl[n], acc[m][n], 0, 0, 0);
            }
    }

    #pragma unroll
    for (int m = 0; m < 4; ++m) {
        const int row = bm * 128 + wr * 64 + m * 16 + (lane >> 4) * 4;
        #pragma unroll
        for (int n = 0; n < 4; ++n) {
            const int col = bn * 128 + wc * 64 + n * 16 + (lane & 15);
            f32x4 v = acc[m][n];
            #pragma unroll
            for (int j = 0; j < 4; ++j)
                U[(size_t)(row + j) * RSV + col] = v[j];
        }
    }
}

__global__ __launch_bounds__(64) void esn_recur_fb(float* __restrict__ OUT,
                                                   const float* __restrict__ D) {
    const int gid = blockIdx.x * 64 + threadIdx.x;
    const int b = gid >> 9;
    const int r = gid & (RSV - 1);
    float* base = OUT + (size_t)b * SEQT * RSV + r;
    const float dK = D[r] * K2LOG2E;
    float s = 0.0f;

    float bA[8], bB[8], bC[8], bD[8];
    #pragma unroll
    for (int j = 0; j < 8; ++j) bA[j] = base[(size_t)(1 + j) * RSV];
    #pragma unroll
    for (int j = 0; j < 8; ++j) bB[j] = base[(size_t)(9 + j) * RSV];
    #pragma unroll
    for (int j = 0; j < 8; ++j) bC[j] = base[(size_t)(17 + j) * RSV];
    #pragma unroll
    for (int j = 0; j < 8; ++j) bD[j] = base[(size_t)(25 + j) * RSV];

#define PROC8B(buf, tt) do {                                  \
    _Pragma("unroll")                                         \
    for (int j = 0; j < 8; ++j) {                             \
        s = esn_step(s, buf[j], dK);                          \
        base[(size_t)((tt) + j) * RSV] = s;                   \
        int idx = (tt) + 33 + j;                              \
        idx = idx < SEQT ? idx : SEQT - 1;                    \
        buf[j] = base[(size_t)idx * RSV];                     \
    }                                                         \
} while (0)

    int t = 0;
    for (int it = 0; it < 63; ++it) {
        PROC8B(bA, t);
        PROC8B(bB, t + 8);
        PROC8B(bC, t + 16);
        PROC8B(bD, t + 24);
        t += 32;
    }
#undef PROC8B
    #pragma unroll
    for (int j = 0; j < 8; ++j) { s = esn_step(s, bA[j], dK); base[(size_t)(2016 + j) * RSV] = s; }
    #pragma unroll
    for (int j = 0; j < 8; ++j) { s = esn_step(s, bB[j], dK); base[(size_t)(2024 + j) * RSV] = s; }
    #pragma unroll
    for (int j = 0; j < 8; ++j) { s = esn_step(s, bC[j], dK); base[(size_t)(2032 + j) * RSV] = s; }
    #pragma unroll
    for (int j = 0; j < 7; ++j) { s = esn_step(s, bD[j], dK); base[(size_t)(2040 + j) * RSV] = s; }

    base[(size_t)(SEQT - 1) * RSV] = 0.0f;
}

extern "C" void kernel_launch(void* const* d_in, const int* in_sizes, int n_in,
                              void* d_out, int out_size, void* d_ws, size_t ws_size,
                              hipStream_t stream) {
    const float* X = (const float*)d_in[0];   // [32,2048,256] fp32
    const float* W = (const float*)d_in[1];   // [512,256] fp32
    const float* D = (const float*)d_in[2];   // [512] fp32
    float* OUT = (float*)d_out;               // [32,2048,512] fp32

    const size_t W16T_BYTES = (size_t)2 * RSV * INSZ * sizeof(_Float16);   // 512 KB
    const size_t U16_BYTES  = (size_t)MTOT * RSV * sizeof(_Float16);       // 64 MB
    if (ws_size >= W16T_BYTES + U16_BYTES) {
        _Float16* W16T = (_Float16*)d_ws;
        _Float16* U16  = (_Float16*)((char*)d_ws + W16T_BYTES);
        esn_convw<<<dim3(64), dim3(256), 0, stream>>>(W, W16T);
        esn_gemm_f<<<dim3((MTOT / BMR) * (RSV / BNR)), dim3(256), 0, stream>>>(X, W16T, U16);
        esn_recur_f<<<dim3(BATCH * 16 * 2), dim3(256), 0, stream>>>(U16, D, OUT);
    } else {
        esn_gemm_fb<<<dim3((MTOT / 128) * (RSV / 128)), dim3(256), 0, stream>>>(X, W, OUT);
        esn_recur_fb<<<dim3(BATCH * RSV / 64), dim3(64), 0, stream>>>(OUT, D);
    }
}

// Round 8
// 271.575 us; speedup vs baseline: 1.4439x; 1.4439x over previous
//
#include <hip/hip_runtime.h>

#define BATCH 32
#define SEQT  2048
#define INSZ  256
#define RSV   512
#define MTOT  (BATCH * SEQT)   // 65536 GEMM rows
#define BM 128
#define BN 128
#define BK 32
#define NK  (INSZ / BK)        // 8 K-steps
#define LSA 40                 // fallback A LDS row stride (f16)
#define ASTR 1040              // A LDS q-stride in f16 (2080 B)
#define LOPLANE 131072         // f16 offset of lo plane in W16T

#define K2LOG2E 2.8853900817779268f  // 2*log2(e)

using f16x8 = __attribute__((ext_vector_type(8))) _Float16;
using f16x4 = __attribute__((ext_vector_type(4))) _Float16;
using f32x4 = __attribute__((ext_vector_type(4))) float;

typedef __attribute__((address_space(1))) unsigned int as1_u32;
typedef __attribute__((address_space(3))) unsigned int as3_u32;
#define GLDS16(gp, lp) __builtin_amdgcn_global_load_lds((as1_u32*)(gp), (as3_u32*)(lp), 16, 0, 0)

// s' = tanh(d*s + u) via exp2; dK = d*2log2e.
static __device__ __forceinline__ float esn_step(float s, float u, float dK) {
    float z  = __builtin_fmaf(dK, s, u * K2LOG2E);
    float e  = __builtin_amdgcn_exp2f(z);
    float rc = __builtin_amdgcn_rcpf(1.0f + e);
    return __builtin_fmaf(-2.0f, rc, 1.0f);
}

// ---------------- fast path ----------------

// W [512][256] fp32 -> W16T: GLDS-chunk-major hi/lo f16 planes (r4 layout).
// Chunk i (16 B): bn=i>>12, ks=(i>>9)&7, c=i&511, q=c>>7, row=c&127;
// holds W[bn*128+row][ks*32+q*8 .. +7]. Linear GLDS write lands [q][row] in LDS.
__global__ __launch_bounds__(256) void esn_convw(const float* __restrict__ W,
                                                 _Float16* __restrict__ W16T) {
    const int i = blockIdx.x * 256 + threadIdx.x;   // 0..16383
    const int bn = i >> 12, ks = (i >> 9) & 7, c = i & 511;
    const int q = c >> 7, row = c & 127;
    const float* src = W + (size_t)(bn * 128 + row) * INSZ + ks * 32 + q * 8;
    float4 v0 = *(const float4*)src;
    float4 v1 = *(const float4*)(src + 4);
    float w8[8] = {v0.x, v0.y, v0.z, v0.w, v1.x, v1.y, v1.z, v1.w};
    f16x8 h, l;
    #pragma unroll
    for (int j = 0; j < 8; ++j) {
        _Float16 hh = (_Float16)w8[j];
        h[j] = hh;
        l[j] = (_Float16)(w8[j] - (float)hh);
    }
    *(f16x8*)(W16T + (size_t)i * 8) = h;
    *(f16x8*)(W16T + LOPLANE + (size_t)i * 8) = l;
}

// u[m][r] = sum_k X[m][k]*W[r][k]; 2-pass f16 hi/lo. r4 staging (GLDS B pre-tiled,
// A reg-convert -> padded q-major LDS) + 2-phase pipeline: double-buffered LDS,
// stage(ks+1) ISSUED before compute(ks), one barrier per ks. Swapped-operand MFMA
// -> lane r-run = 4 consecutive r -> packed f16x4 epilogue. Output u16 [m][r] f16.
__global__ __launch_bounds__(256) void esn_gemm_f(const float* __restrict__ X,
                                                  const _Float16* __restrict__ W16T,
                                                  _Float16* __restrict__ U16) {
    __shared__ _Float16 Ash[2][4 * ASTR];   // 2 x 8320 B, [q][row][8] padded
    __shared__ _Float16 Bh[2][4096];        // 2 x 8 KB, [q][row][8] linear (GLDS dest)
    __shared__ _Float16 Bl[2][4096];

    const int tid  = threadIdx.x;
    const int lane = tid & 63;
    const int wid  = tid >> 6;
    const int wr   = wid >> 1, wc = wid & 1;
    // chunked XCD swizzle: bn-siblings of one bm adjacent on one XCD
    const int lgc = (blockIdx.x & 7) * 256 + (blockIdx.x >> 3);
    const int bm = lgc >> 2, bn = lgc & 3;

    const int srow = tid >> 3;            // 0..31
    const int scol = (tid & 7) * 4;       // 0,4,...,28
    const int qa   = scol >> 3;           // 0..3
    const int ha   = (scol >> 2) & 1;

    f32x4 acc[4][4] = {};

    // ---- prologue: stage ks=0 into buffer 0 ----
    #pragma unroll
    for (int j = 0; j < 2; ++j) {
        const int cb = (wid * 2 + j) * 64;
        const _Float16* gh = W16T + ((size_t)(bn * 8 + 0) * 512 + cb + lane) * 8;
        GLDS16(gh, &Bh[0][cb * 8]);
        GLDS16(gh + LOPLANE, &Bl[0][cb * 8]);
    }
    #pragma unroll
    for (int p = 0; p < 4; ++p) {
        const int row = srow + p * 32;
        float4 av = *(const float4*)(X + (size_t)(bm * BM + row) * INSZ + scol);
        float a4[4] = {av.x, av.y, av.z, av.w};
        f16x4 ah;
        #pragma unroll
        for (int j = 0; j < 4; ++j) ah[j] = (_Float16)a4[j];
        *(f16x4*)&Ash[0][qa * ASTR + row * 8 + ha * 4] = ah;
    }
    __syncthreads();

    // ---- main loop: one barrier per ks; stage(ks+1) issued before compute(ks) ----
    #pragma unroll
    for (int ks = 0; ks < NK; ++ks) {
        const int cur = ks & 1, nxt = cur ^ 1;
        float4 xr[4];
        if (ks + 1 < NK) {
            #pragma unroll
            for (int j = 0; j < 2; ++j) {   // B DMA for ks+1 (no reg dependency)
                const int cb = (wid * 2 + j) * 64;
                const _Float16* gh = W16T + ((size_t)(bn * 8 + ks + 1) * 512 + cb + lane) * 8;
                GLDS16(gh, &Bh[nxt][cb * 8]);
                GLDS16(gh + LOPLANE, &Bl[nxt][cb * 8]);
            }
            #pragma unroll
            for (int p = 0; p < 4; ++p) {   // A loads for ks+1 (consumed after MFMAs)
                const int row = srow + p * 32;
                xr[p] = *(const float4*)(X + (size_t)(bm * BM + row) * INSZ + (ks + 1) * BK + scol);
            }
        }

        // ---- compute ks from buffer cur ----
        f16x8 af[4], bfh[4], bfl[4];
        const int qf = lane >> 4;
        #pragma unroll
        for (int m = 0; m < 4; ++m)
            af[m] = *(const f16x8*)&Ash[cur][qf * ASTR + (wr * 64 + m * 16 + (lane & 15)) * 8];
        #pragma unroll
        for (int n = 0; n < 4; ++n) {
            const int rr = qf * 1024 + (wc * 64 + n * 16 + (lane & 15)) * 8;
            bfh[n] = *(const f16x8*)&Bh[cur][rr];
            bfl[n] = *(const f16x8*)&Bl[cur][rr];
        }
        #pragma unroll
        for (int m = 0; m < 4; ++m)
            #pragma unroll
            for (int n = 0; n < 4; ++n) {
                // swapped operands: D rows = W rows (lane reg-run), D cols = X rows
                acc[m][n] = __builtin_amdgcn_mfma_f32_16x16x32_f16(bfh[n], af[m], acc[m][n], 0, 0, 0);
                acc[m][n] = __builtin_amdgcn_mfma_f32_16x16x32_f16(bfl[n], af[m], acc[m][n], 0, 0, 0);
            }

        if (ks + 1 < NK) {
            #pragma unroll
            for (int p = 0; p < 4; ++p) {   // convert + LDS-write A(ks+1)
                const int row = srow + p * 32;
                float a4[4] = {xr[p].x, xr[p].y, xr[p].z, xr[p].w};
                f16x4 ah;
                #pragma unroll
                for (int j = 0; j < 4; ++j) ah[j] = (_Float16)a4[j];
                *(f16x4*)&Ash[nxt][qa * ASTR + row * 8 + ha * 4] = ah;
            }
        }
        __syncthreads();
    }

    // ---- epilogue: lane holds 4 consecutive r per (m,n); packed f16x4 stores ----
    #pragma unroll
    for (int m = 0; m < 4; ++m) {
        const int gm = bm * BM + wr * 64 + m * 16 + (lane & 15);
        #pragma unroll
        for (int n = 0; n < 4; ++n) {
            const int gr = bn * BN + wc * 64 + n * 16 + (lane >> 4) * 4;
            f16x4 o;
            #pragma unroll
            for (int j = 0; j < 4; ++j) o[j] = (_Float16)acc[m][n][j];
            *(f16x4*)(U16 + (size_t)gm * RSV + gr) = o;
        }
    }
}

// Parallel-in-time recurrence (r4-proven): 8 segments of 256 steps, 32-step warmup
// from zero (|d|<=0.5 => err <= 2^-32). u16 [b][t][r] coalesced reads; OUT coalesced
// writes. 512 blocks -> 8 waves/CU TLP, 17-deep register prefetch ILP.
__global__ __launch_bounds__(256) void esn_recur_f(const _Float16* __restrict__ U16,
                                                   const float* __restrict__ D,
                                                   float* __restrict__ OUT) {
    const int tid  = threadIdx.x;
    const int b    = blockIdx.x >> 4;
    const int seg  = (blockIdx.x >> 1) & 7;
    const int half = blockIdx.x & 1;
    const int r    = half * 256 + tid;

    const _Float16* ub = U16 + (size_t)b * SEQT * RSV + r;
    float* ob = OUT + (size_t)b * SEQT * RSV + r;
    const float dK = D[r] * K2LOG2E;
    const int t0 = seg * 256;

    float s = 0.0f;
    if (seg) {
        #pragma unroll 8
        for (int k = 0; k < 32; ++k)
            s = esn_step(s, (float)ub[(size_t)(t0 - 31 + k) * RSV], dK);
    }

    _Float16 bufA[8], bufB[8];
    #pragma unroll
    for (int j = 0; j < 8; ++j) bufA[j] = ub[(size_t)(t0 + 1 + j) * RSV];
    #pragma unroll
    for (int j = 0; j < 8; ++j) bufB[j] = ub[(size_t)(t0 + 9 + j) * RSV];

#define PROC8F(buf, tt) do {                                  \
    _Pragma("unroll")                                         \
    for (int j = 0; j < 8; ++j) {                             \
        s = esn_step(s, (float)buf[j], dK);                   \
        ob[(size_t)((tt) + j) * RSV] = s;                     \
        int idx = (tt) + j + 17;                              \
        idx = idx < SEQT ? idx : SEQT - 1;                    \
        buf[j] = ub[(size_t)idx * RSV];                       \
    }                                                         \
} while (0)

    int t = t0;
    for (int it = 0; it < 16; ++it) {   // 16*16 = 256 steps
        PROC8F(bufA, t);
        PROC8F(bufB, t + 8);
        t += 16;
    }
#undef PROC8F
    if (seg == 7) ob[(size_t)(SEQT - 1) * RSV] = 0.0f;
}

// ---------------- fallback path (no workspace; round-2 kernels, in-place) ----------------

__global__ __launch_bounds__(256) void esn_gemm_fb(const float* __restrict__ X,
                                                   const float* __restrict__ W,
                                                   float* __restrict__ U) {
    __shared__ _Float16 Ash[128 * LSA];
    __shared__ _Float16 Bsh[128 * 72];

    const int tid  = threadIdx.x;
    const int lane = tid & 63;
    const int wid  = tid >> 6;
    const int wr   = wid >> 1, wc = wid & 1;
    const int bm   = blockIdx.x >> 2, bn = blockIdx.x & 3;
    const int srow = tid >> 3;
    const int scol = (tid & 7) * 4;

    f32x4 acc[4][4] = {};

    for (int ks = 0; ks < NK; ++ks) {
        __syncthreads();
        #pragma unroll
        for (int p = 0; p < 4; ++p) {
            const int row = srow + p * 32;
            float4 av = *(const float4*)(X + (size_t)(bm * 128 + row) * INSZ + ks * 32 + scol);
            float4 bv = *(const float4*)(W + (size_t)(bn * 128 + row) * INSZ + ks * 32 + scol);
            float a4[4] = {av.x, av.y, av.z, av.w};
            float b4[4] = {bv.x, bv.y, bv.z, bv.w};
            f16x4 ah, bh, bl;
            #pragma unroll
            for (int j = 0; j < 4; ++j) {
                ah[j] = (_Float16)a4[j];
                _Float16 h = (_Float16)b4[j];
                bh[j] = h;
                bl[j] = (_Float16)(b4[j] - (float)h);
            }
            *(f16x4*)&Ash[row * LSA + scol] = ah;
            *(f16x4*)&Bsh[row * 72 + scol] = bh;
            *(f16x4*)&Bsh[row * 72 + 32 + scol] = bl;
        }
        __syncthreads();

        f16x8 af[4], bfh[4], bfl[4];
        #pragma unroll
        for (int m = 0; m < 4; ++m)
            af[m] = *(const f16x8*)&Ash[(wr * 64 + m * 16 + (lane & 15)) * LSA + (lane >> 4) * 8];
        #pragma unroll
        for (int n = 0; n < 4; ++n) {
            const _Float16* p = &Bsh[(wc * 64 + n * 16 + (lane & 15)) * 72 + (lane >> 4) * 8];
            bfh[n] = *(const f16x8*)p;
            bfl[n] = *(const f16x8*)(p + 32);
        }
        #pragma unroll
        for (int m = 0; m < 4; ++m)
            #pragma unroll
            for (int n = 0; n < 4; ++n) {
                acc[m][n] = __builtin_amdgcn_mfma_f32_16x16x32_f16(af[m], bfh[n], acc[m][n], 0, 0, 0);
                acc[m][n] = __builtin_amdgcn_mfma_f32_16x16x32_f16(af[m], bfl[n], acc[m][n], 0, 0, 0);
            }
    }

    #pragma unroll
    for (int m = 0; m < 4; ++m) {
        const int row = bm * 128 + wr * 64 + m * 16 + (lane >> 4) * 4;
        #pragma unroll
        for (int n = 0; n < 4; ++n) {
            const int col = bn * 128 + wc * 64 + n * 16 + (lane & 15);
            f32x4 v = acc[m][n];
            #pragma unroll
            for (int j = 0; j < 4; ++j)
                U[(size_t)(row + j) * RSV + col] = v[j];
        }
    }
}

__global__ __launch_bounds__(64) void esn_recur_fb(float* __restrict__ OUT,
                                                   const float* __restrict__ D) {
    const int gid = blockIdx.x * 64 + threadIdx.x;
    const int b = gid >> 9;
    const int r = gid & (RSV - 1);
    float* base = OUT + (size_t)b * SEQT * RSV + r;
    const float dK = D[r] * K2LOG2E;
    float s = 0.0f;

    float bA[8], bB[8], bC[8], bD[8];
    #pragma unroll
    for (int j = 0; j < 8; ++j) bA[j] = base[(size_t)(1 + j) * RSV];
    #pragma unroll
    for (int j = 0; j < 8; ++j) bB[j] = base[(size_t)(9 + j) * RSV];
    #pragma unroll
    for (int j = 0; j < 8; ++j) bC[j] = base[(size_t)(17 + j) * RSV];
    #pragma unroll
    for (int j = 0; j < 8; ++j) bD[j] = base[(size_t)(25 + j) * RSV];

#define PROC8B(buf, tt) do {                                  \
    _Pragma("unroll")                                         \
    for (int j = 0; j < 8; ++j) {                             \
        s = esn_step(s, buf[j], dK);                          \
        base[(size_t)((tt) + j) * RSV] = s;                   \
        int idx = (tt) + 33 + j;                              \
        idx = idx < SEQT ? idx : SEQT - 1;                    \
        buf[j] = base[(size_t)idx * RSV];                     \
    }                                                         \
} while (0)

    int t = 0;
    for (int it = 0; it < 63; ++it) {
        PROC8B(bA, t);
        PROC8B(bB, t + 8);
        PROC8B(bC, t + 16);
        PROC8B(bD, t + 24);
        t += 32;
    }
#undef PROC8B
    #pragma unroll
    for (int j = 0; j < 8; ++j) { s = esn_step(s, bA[j], dK); base[(size_t)(2016 + j) * RSV] = s; }
    #pragma unroll
    for (int j = 0; j < 8; ++j) { s = esn_step(s, bB[j], dK); base[(size_t)(2024 + j) * RSV] = s; }
    #pragma unroll
    for (int j = 0; j < 8; ++j) { s = esn_step(s, bC[j], dK); base[(size_t)(2032 + j) * RSV] = s; }
    #pragma unroll
    for (int j = 0; j < 7; ++j) { s = esn_step(s, bD[j], dK); base[(size_t)(2040 + j) * RSV] = s; }

    base[(size_t)(SEQT - 1) * RSV] = 0.0f;
}

extern "C" void kernel_launch(void* const* d_in, const int* in_sizes, int n_in,
                              void* d_out, int out_size, void* d_ws, size_t ws_size,
                              hipStream_t stream) {
    const float* X = (const float*)d_in[0];   // [32,2048,256] fp32
    const float* W = (const float*)d_in[1];   // [512,256] fp32
    const float* D = (const float*)d_in[2];   // [512] fp32
    float* OUT = (float*)d_out;               // [32,2048,512] fp32

    const size_t W16T_BYTES = (size_t)2 * RSV * INSZ * sizeof(_Float16);   // 512 KB
    const size_t U16_BYTES  = (size_t)MTOT * RSV * sizeof(_Float16);       // 64 MB
    if (ws_size >= W16T_BYTES + U16_BYTES) {
        _Float16* W16T = (_Float16*)d_ws;
        _Float16* U16  = (_Float16*)((char*)d_ws + W16T_BYTES);
        esn_convw<<<dim3(64), dim3(256), 0, stream>>>(W, W16T);
        esn_gemm_f<<<dim3((MTOT / BM) * (RSV / BN)), dim3(256), 0, stream>>>(X, W16T, U16);
        esn_recur_f<<<dim3(BATCH * 8 * 2), dim3(256), 0, stream>>>(U16, D, OUT);
    } else {
        esn_gemm_fb<<<dim3((MTOT / 128) * (RSV / 128)), dim3(256), 0, stream>>>(X, W, OUT);
        esn_recur_fb<<<dim3(BATCH * RSV / 64), dim3(64), 0, stream>>>(OUT, D);
    }
}